// Round 10
// baseline (581.854 us; speedup 1.0000x reference)
//
#include <hip/hip_runtime.h>
#include <math.h>

#define EMB 768
#define NH 12
#define HD 64
#define NL 12
#define NV 50257
#define MAXS 1024
#define S_PAST 1023
#define E3 2304
#define E4 3072

// workspace float offsets: h ping-pong buffers + qkv + attention partials
#define WS_HA   0
#define WS_HB   768
#define WS_QKV  1536
#define WS_PART 3840   // 192 entries * 68 floats

__device__ __forceinline__ void f4add(float4& a, const float4& b) {
  a.x += b.x; a.y += b.y; a.z += b.z; a.w += b.w;
}
__device__ __forceinline__ void f4fma(float4& a, float x, const float4& w) {
  a.x += x * w.x; a.y += x * w.y; a.z += x * w.z; a.w += x * w.w;
}

__device__ __forceinline__ void blockReduce2(float& a, float& b, volatile float* ra, volatile float* rb) {
  int lane = threadIdx.x & 63, wid = threadIdx.x >> 6;
#pragma unroll
  for (int o = 32; o > 0; o >>= 1) { a += __shfl_down(a, o); b += __shfl_down(b, o); }
  if (lane == 0) { ra[wid] = a; rb[wid] = b; }
  __syncthreads();
  if (threadIdx.x == 0) {
    ra[0] = ra[0] + ra[1] + ra[2] + ra[3];
    rb[0] = rb[0] + rb[1] + rb[2] + rb[3];
  }
  __syncthreads();
  a = ra[0]; b = rb[0];
}

__device__ __forceinline__ float gelu(float x) {
  return 0.5f * x * (1.f + tanhf(0.7978845608028654f * (x + 0.044715f * x * x * x)));
}

// h(A) = wte[id] + wpe[S]; seed layer-0 qkv bias
__global__ void init_kernel(const int* __restrict__ ids, const float* __restrict__ wte,
                            const float* __restrict__ wpe, const float* __restrict__ attn_b,
                            float* __restrict__ wsf) {
  int idx = blockIdx.x * 256 + threadIdx.x;
  if (idx < E3) wsf[WS_QKV + idx] = attn_b[idx];
  if (idx < EMB) {
    int id = ids[0];
    wsf[WS_HA + idx] = wte[(size_t)id * EMB + idx] + wpe[(size_t)S_PAST * EMB + idx];
  }
}

// qkv: out[j] += sum_e LN1(h)[e] * attn_w[l][e][j]; 32 rows x 256 cols per block.
// Block (0,0) also refreshes the shadow h buffer (single writer; no one reads S here).
__global__ void ln_gemv4(const float* __restrict__ hvec, float* __restrict__ shadow,
                         const float* __restrict__ g, const float* __restrict__ bb,
                         const float* __restrict__ W, float* __restrict__ out, int l) {
  __shared__ float lh[EMB];
  __shared__ float xs[32];
  __shared__ float ra[4], rb[4];
  __shared__ float4 red[4][64];
  int tid = threadIdx.x, lane = tid & 63, wid = tid >> 6;
  int e0 = blockIdx.y * 32;
  float hv0 = hvec[tid], hv1 = hvec[tid + 256], hv2 = hvec[tid + 512];
  int j4 = blockIdx.x * 64 + lane;
  const int N4 = E3 >> 2;
  const float4* p = (const float4*)(W + (size_t)l * EMB * E3) + (size_t)(e0 + wid) * N4 + j4;
  float4 w[8];
#pragma unroll
  for (int i = 0; i < 8; i++) w[i] = p[(size_t)(i * 4) * N4];
  float gv = 0.f, bv = 0.f;
  if (tid < 32) { gv = g[l * EMB + e0 + tid]; bv = bb[l * EMB + e0 + tid]; }
  if (blockIdx.x == 0 && blockIdx.y == 0) {
    shadow[tid] = hv0; shadow[tid + 256] = hv1; shadow[tid + 512] = hv2;
  }
  lh[tid] = hv0; lh[tid + 256] = hv1; lh[tid + 512] = hv2;
  float s1 = hv0 + hv1 + hv2;
  float s2 = hv0 * hv0 + hv1 * hv1 + hv2 * hv2;
  blockReduce2(s1, s2, ra, rb);
  float mean = s1 * (1.f / EMB);
  float var = s2 * (1.f / EMB) - mean * mean;
  float rstd = rsqrtf(var + 1e-5f);
  if (tid < 32) xs[tid] = (lh[e0 + tid] - mean) * rstd * gv + bv;
  __syncthreads();
  float4 acc = {0.f, 0.f, 0.f, 0.f};
#pragma unroll
  for (int i = 0; i < 8; i++) f4fma(acc, xs[wid + i * 4], w[i]);
  red[wid][lane] = acc;
  __syncthreads();
  if (wid == 0) {
    float4 a0 = red[0][lane], a1 = red[1][lane], a2 = red[2][lane], a3 = red[3][lane];
    float rx = a0.x + a1.x + a2.x + a3.x;
    float ry = a0.y + a1.y + a2.y + a3.y;
    float rz = a0.z + a1.z + a2.z + a3.z;
    float rw = a0.w + a1.w + a2.w + a3.w;
    float* op = out + (size_t)j4 * 4;
    atomicAdd(op + 0, rx); atomicAdd(op + 1, ry);
    atomicAdd(op + 2, rz); atomicAdd(op + 3, rw);
  }
}

// attention partials for one (head, 64-key chunk); each block also copies its K/V
// chunk to the output cache (new slot S_PAST comes from qkv).
__global__ void attn_kv(const float* __restrict__ qkv, const float* __restrict__ pk,
                        const float* __restrict__ pv, const float* __restrict__ mask,
                        float* __restrict__ opk, float* __restrict__ opv,
                        float* __restrict__ part, int l) {
  int h = blockIdx.x >> 4, c = blockIdx.x & 15;
  int tid = threadIdx.x, lane = tid & 63, wid = tid >> 6;
  int sub = tid & 15, grp = tid >> 4;
  __shared__ float4 qs4[16];
  __shared__ float sc[64];
  __shared__ float4 redo[4][16];
  if (tid < 16) qs4[tid] = ((const float4*)(qkv + h * 64))[tid];
  __syncthreads();
  size_t base = ((size_t)(l * NH + h) * MAXS) * HD;
  const float4* K4 = (const float4*)(pk + base);
  const float4* V4 = (const float4*)(pv + base);
  float4* oK4 = (float4*)(opk + base);
  float4* oV4 = (float4*)(opv + base);
  int t0 = c * 64;
  float4 kreg[4];
#pragma unroll
  for (int i = 0; i < 4; i++) {
    int t = t0 + grp + i * 16;
    kreg[i] = (t == S_PAST) ? ((const float4*)(qkv + EMB + h * 64))[sub] : K4[(size_t)t * 16 + sub];
  }
#pragma unroll
  for (int i = 0; i < 4; i++) {
    int t = t0 + grp + i * 16;
    oK4[(size_t)t * 16 + sub] = kreg[i];
  }
  float4 q4 = qs4[sub];
#pragma unroll
  for (int i = 0; i < 4; i++) {
    int key = grp + i * 16;
    float p = q4.x * kreg[i].x + q4.y * kreg[i].y + q4.z * kreg[i].z + q4.w * kreg[i].w;
    p += __shfl_xor(p, 1); p += __shfl_xor(p, 2);
    p += __shfl_xor(p, 4); p += __shfl_xor(p, 8);
    if (sub == 0) sc[key] = p * 0.125f + (1.f - mask[t0 + key]) * (-1e9f);
  }
  __syncthreads();
  if (wid == 0) {
    float a = sc[lane];
    float m = a;
#pragma unroll
    for (int o = 32; o > 0; o >>= 1) m = fmaxf(m, __shfl_down(m, o));
    m = __shfl(m, 0);
    float ea = expf(a - m);
    sc[lane] = ea;
    float s = ea;
#pragma unroll
    for (int o = 32; o > 0; o >>= 1) s += __shfl_down(s, o);
    if (lane == 0) { part[(h * 16 + c) * 68 + 0] = m; part[(h * 16 + c) * 68 + 1] = s; }
  }
  __syncthreads();
  float4 vreg[4];
#pragma unroll
  for (int i = 0; i < 4; i++) {
    int t = t0 + grp + i * 16;
    vreg[i] = (t == S_PAST) ? ((const float4*)(qkv + 2 * EMB + h * 64))[sub] : V4[(size_t)t * 16 + sub];
  }
#pragma unroll
  for (int i = 0; i < 4; i++) {
    int t = t0 + grp + i * 16;
    oV4[(size_t)t * 16 + sub] = vreg[i];
  }
  float4 acc = {0.f, 0.f, 0.f, 0.f};
#pragma unroll
  for (int i = 0; i < 4; i++) f4fma(acc, sc[grp + i * 16], vreg[i]);
  acc.x += __shfl_xor(acc.x, 16); acc.y += __shfl_xor(acc.y, 16);
  acc.z += __shfl_xor(acc.z, 16); acc.w += __shfl_xor(acc.w, 16);
  acc.x += __shfl_xor(acc.x, 32); acc.y += __shfl_xor(acc.y, 32);
  acc.z += __shfl_xor(acc.z, 32); acc.w += __shfl_xor(acc.w, 32);
  if (lane < 16) redo[wid][lane] = acc;
  __syncthreads();
  if (tid < 16) {
    float4 a0 = redo[0][tid], a1 = redo[1][tid], a2 = redo[2][tid], a3 = redo[3][tid];
    float4 r;
    r.x = a0.x + a1.x + a2.x + a3.x;
    r.y = a0.y + a1.y + a2.y + a3.y;
    r.z = a0.z + a1.z + a2.z + a3.z;
    r.w = a0.w + a1.w + a2.w + a3.w;
    ((float4*)(part + (h * 16 + c) * 68 + 4))[tid] = r;
  }
}

// combine 16 chunk-partials (16-dim slice of head), then 16-row GEMV into BOTH h buffers
__global__ void proj_attn(const float* __restrict__ part, const float* __restrict__ W,
                          const float* __restrict__ bias, float* __restrict__ houtR,
                          float* __restrict__ houtS, int l) {
  int jb = blockIdx.x;           // 0..2 col tile
  int rt = blockIdx.y;           // 0..47 row tile (16 rows)
  int h = rt >> 2, esub = rt & 3;
  int tid = threadIdx.x, lane = tid & 63, wid = tid >> 6;
  __shared__ float xs[16];
  __shared__ float4 red[4][64];
  int j4 = jb * 64 + lane;
  const int N4 = EMB >> 2;
  int r0 = h * 64 + esub * 16;
  const float4* p = (const float4*)(W + (size_t)l * EMB * EMB) + (size_t)(r0 + wid) * N4 + j4;
  float4 w[4];
#pragma unroll
  for (int i = 0; i < 4; i++) w[i] = p[(size_t)(i * 4) * N4];
  if (tid < 16) {
    float M = -1e30f;
#pragma unroll
    for (int q = 0; q < 16; q++) M = fmaxf(M, part[(h * 16 + q) * 68]);
    float T = 0.f, o = 0.f;
    int d = esub * 16 + tid;
#pragma unroll
    for (int q = 0; q < 16; q++) {
      float wq = expf(part[(h * 16 + q) * 68] - M);
      T += part[(h * 16 + q) * 68 + 1] * wq;
      o += part[(h * 16 + q) * 68 + 4 + d] * wq;
    }
    xs[tid] = o / T;
  }
  __syncthreads();
  float4 acc = {0.f, 0.f, 0.f, 0.f};
#pragma unroll
  for (int i = 0; i < 4; i++) f4fma(acc, xs[wid + i * 4], w[i]);
  red[wid][lane] = acc;
  __syncthreads();
  if (wid == 0) {
    float4 a0 = red[0][lane], a1 = red[1][lane], a2 = red[2][lane], a3 = red[3][lane];
    float rx = a0.x + a1.x + a2.x + a3.x;
    float ry = a0.y + a1.y + a2.y + a3.y;
    float rz = a0.z + a1.z + a2.z + a3.z;
    float rw = a0.w + a1.w + a2.w + a3.w;
    if (rt == 0) {
      const float* bp = bias + l * EMB + jb * 256 + lane * 4;
      rx += bp[0]; ry += bp[1]; rz += bp[2]; rw += bp[3];
    }
    size_t off = (size_t)jb * 256 + (size_t)lane * 4;
    float* op1 = houtR + off;
    atomicAdd(op1 + 0, rx); atomicAdd(op1 + 1, ry);
    atomicAdd(op1 + 2, rz); atomicAdd(op1 + 3, rw);
    float* op2 = houtS + off;
    atomicAdd(op2 + 0, rx); atomicAdd(op2 + 1, ry);
    atomicAdd(op2 + 2, rz); atomicAdd(op2 + 3, rw);
  }
}

// fused fc+mlp, column-sliced: block bi owns fc columns J=[bi*16, bi*16+16).
// Computes fc[J] = LN2(h) @ fc_w[:,J] (+bias), gelu, then h(S) += gelu(fc[J]) @ mlp_w[J,:].
// Reads R only, writes S only (shadow ping-pong: no read/write race). Zero redundant traffic.
__global__ __launch_bounds__(256) void fcmlp(
    const float* __restrict__ hvec, float* __restrict__ hshadow,
    const float* __restrict__ g2, const float* __restrict__ b2,
    const float* __restrict__ fc_w, const float* __restrict__ fc_b,
    const float* __restrict__ mlp_w, const float* __restrict__ mlp_b,
    const float* __restrict__ attn_b, float* __restrict__ wqkv, int l) {
  __shared__ float xs[EMB];
  __shared__ float ra[4], rb[4];
  __shared__ __align__(16) float4 red[256];
  __shared__ float gl[16];
  __shared__ __align__(16) float4 arr[768];   // 4 warps * 192
  int tid = threadIdx.x, lane = tid & 63, wid = tid >> 6;
  int bi = blockIdx.x;
  // issue h loads
  float hv0 = hvec[tid], hv1 = hvec[tid + 256], hv2 = hvec[tid + 512];
  // issue BOTH weight phases up front (addresses independent of LN result)
  int q = tid & 3, r0 = tid >> 2;
  const float4* WA = (const float4*)(fc_w + (size_t)l * EMB * E4) + (size_t)bi * 4 + q;
  float4 wa[12];
#pragma unroll
  for (int i = 0; i < 12; i++) wa[i] = WA[(size_t)(r0 + 64 * i) * (E4 >> 2)];
  const float4* WB = (const float4*)(mlp_w + (size_t)l * E4 * EMB) + (size_t)(bi * 16 + wid * 4) * (EMB >> 2) + lane;
  float4 wb[12];
#pragma unroll
  for (int i = 0; i < 4; i++)
#pragma unroll
    for (int k = 0; k < 3; k++) wb[i * 3 + k] = WB[(size_t)i * (EMB >> 2) + 64 * k];
  float gv0 = g2[l * EMB + tid], gv1 = g2[l * EMB + tid + 256], gv2 = g2[l * EMB + tid + 512];
  float bv0 = b2[l * EMB + tid], bv1 = b2[l * EMB + tid + 256], bv2 = b2[l * EMB + tid + 512];
  if (l + 1 < NL && bi < 9) wqkv[bi * 256 + tid] = attn_b[(l + 1) * E3 + bi * 256 + tid];
  // LN2 (latency hidden under the weight loads above)
  float s1 = hv0 + hv1 + hv2, s2 = hv0 * hv0 + hv1 * hv1 + hv2 * hv2;
  blockReduce2(s1, s2, ra, rb);
  float mean = s1 * (1.f / EMB);
  float var = s2 * (1.f / EMB) - mean * mean;
  float rstd = rsqrtf(var + 1e-5f);
  xs[tid]       = (hv0 - mean) * rstd * gv0 + bv0;
  xs[tid + 256] = (hv1 - mean) * rstd * gv1 + bv1;
  xs[tid + 512] = (hv2 - mean) * rstd * gv2 + bv2;
  __syncthreads();
  // phase A: fc columns (thread covers rows r0+64i, col-quad q)
  float4 acc = {0.f, 0.f, 0.f, 0.f};
#pragma unroll
  for (int i = 0; i < 12; i++) f4fma(acc, xs[r0 + 64 * i], wa[i]);
  red[tid] = acc;
  __syncthreads();
#pragma unroll
  for (int s = 128; s >= 4; s >>= 1) {
    if (tid < s) f4add(red[tid], red[tid + s]);
    __syncthreads();
  }
  if (tid < 16) gl[tid] = gelu(((const float*)red)[tid] + fc_b[l * E4 + bi * 16 + tid]);
  __syncthreads();
  // phase B: mlp rows J (warp handles 4 rows; lane covers 3 col-quads)
  float4 a0 = {0.f,0.f,0.f,0.f}, a1 = {0.f,0.f,0.f,0.f}, a2 = {0.f,0.f,0.f,0.f};
#pragma unroll
  for (int i = 0; i < 4; i++) {
    float x = gl[wid * 4 + i];
    f4fma(a0, x, wb[i * 3]); f4fma(a1, x, wb[i * 3 + 1]); f4fma(a2, x, wb[i * 3 + 2]);
  }
  arr[wid * 192 + lane] = a0;
  arr[wid * 192 + lane + 64] = a1;
  arr[wid * 192 + lane + 128] = a2;
  __syncthreads();
  if (wid == 0) {
#pragma unroll
    for (int k = 0; k < 3; k++) {
      int cf = lane + 64 * k;
      float4 v = arr[cf];
      f4add(v, arr[192 + cf]); f4add(v, arr[384 + cf]); f4add(v, arr[576 + cf]);
      if (bi == 0) {
        const float* bp = mlp_b + l * EMB + cf * 4;
        v.x += bp[0]; v.y += bp[1]; v.z += bp[2]; v.w += bp[3];
      }
      float* op = hshadow + (size_t)cf * 4;
      atomicAdd(op + 0, v.x); atomicAdd(op + 1, v.y);
      atomicAdd(op + 2, v.z); atomicAdd(op + 3, v.w);
    }
  }
}

// final LN fused into logits
__global__ void logits_lnf(const float* __restrict__ hvec, const float* __restrict__ g,
                           const float* __restrict__ b, const float* __restrict__ wte,
                           float* __restrict__ out) {
  __shared__ __align__(16) float4 xs4[192];
  __shared__ float ra[4], rb[4];
  int tid = threadIdx.x, lane = tid & 63, wid = tid >> 6;
  float hv0 = hvec[tid], hv1 = hvec[tid + 256], hv2 = hvec[tid + 512];
  int v = blockIdx.x * 4 + wid;
  float4 a0 = {0,0,0,0}, a1 = {0,0,0,0}, a2 = {0,0,0,0};
  if (v < NV) {
    const float4* row = (const float4*)(wte + (size_t)v * EMB);
    a0 = row[lane]; a1 = row[lane + 64]; a2 = row[lane + 128];
  }
  float s1 = hv0 + hv1 + hv2;
  float s2 = hv0 * hv0 + hv1 * hv1 + hv2 * hv2;
  blockReduce2(s1, s2, ra, rb);
  float mean = s1 * (1.f / EMB);
  float var = s2 * (1.f / EMB) - mean * mean;
  float rstd = rsqrtf(var + 1e-5f);
  ((float*)xs4)[tid]       = (hv0 - mean) * rstd * g[tid]       + b[tid];
  ((float*)xs4)[tid + 256] = (hv1 - mean) * rstd * g[tid + 256] + b[tid + 256];
  ((float*)xs4)[tid + 512] = (hv2 - mean) * rstd * g[tid + 512] + b[tid + 512];
  __syncthreads();
  if (v >= NV) return;
  float4 x0 = xs4[lane], x1 = xs4[lane + 64], x2 = xs4[lane + 128];
  float acc = a0.x * x0.x + a0.y * x0.y + a0.z * x0.z + a0.w * x0.w
            + a1.x * x1.x + a1.y * x1.y + a1.z * x1.z + a1.w * x1.w
            + a2.x * x2.x + a2.y * x2.y + a2.z * x2.z + a2.w * x2.w;
#pragma unroll
  for (int o = 32; o > 0; o >>= 1) acc += __shfl_down(acc, o);
  if (lane == 0) out[v] = acc;
}

extern "C" void kernel_launch(void* const* d_in, const int* in_sizes, int n_in,
                              void* d_out, int out_size, void* d_ws, size_t ws_size,
                              hipStream_t stream) {
  const int* input_ids = (const int*)d_in[0];
  const float* past_key = (const float*)d_in[1];
  const float* past_value = (const float*)d_in[2];
  const float* mask = (const float*)d_in[4];
  const float* wte = (const float*)d_in[5];
  const float* wpe = (const float*)d_in[6];
  const float* ln1_g = (const float*)d_in[7];
  const float* ln1_b = (const float*)d_in[8];
  const float* attn_w = (const float*)d_in[9];
  const float* attn_b = (const float*)d_in[10];
  const float* proj_w = (const float*)d_in[11];
  const float* proj_b = (const float*)d_in[12];
  const float* ln2_g = (const float*)d_in[13];
  const float* ln2_b = (const float*)d_in[14];
  const float* fc_w = (const float*)d_in[15];
  const float* fc_b = (const float*)d_in[16];
  const float* mlp_w = (const float*)d_in[17];
  const float* mlp_b = (const float*)d_in[18];
  const float* lnf_g = (const float*)d_in[19];
  const float* lnf_b = (const float*)d_in[20];

  float* out = (float*)d_out;
  float* out_logits = out;
  float* out_pk = out + NV;
  float* out_pv = out_pk + (size_t)NL * NH * MAXS * HD;

  float* wsf = (float*)d_ws;
  float* wqkv = wsf + WS_QKV;
  float* wpart = wsf + WS_PART;

  init_kernel<<<9, 256, 0, stream>>>(input_ids, wte, wpe, attn_b, wsf);

  for (int l = 0; l < NL; l++) {
    float* R = wsf + ((l & 1) ? WS_HB : WS_HA);
    float* S = wsf + ((l & 1) ? WS_HA : WS_HB);
    ln_gemv4<<<dim3(9, 24), 256, 0, stream>>>(R, S, ln1_g, ln1_b, attn_w, wqkv, l);
    attn_kv<<<192, 256, 0, stream>>>(wqkv, past_key, past_value, mask, out_pk, out_pv, wpart, l);
    proj_attn<<<dim3(3, 48), 256, 0, stream>>>(wpart, proj_w, proj_b, R, S, l);
    fcmlp<<<192, 256, 0, stream>>>(R, S, ln2_g, ln2_b, fc_w, fc_b, mlp_w, mlp_b,
                                   attn_b, wqkv, l);
  }
  logits_lnf<<<12565, 256, 0, stream>>>(wsf + WS_HA, lnf_g, lnf_b, wte, out_logits);
}

// Round 11
// 458.758 us; speedup vs baseline: 1.2683x; 1.2683x over previous
//
#include <hip/hip_runtime.h>
#include <math.h>

#define EMB 768
#define NH 12
#define HD 64
#define NL 12
#define NV 50257
#define MAXS 1024
#define S_PAST 1023
#define E3 2304
#define E4 3072

// workspace float offsets
#define WS_HA   0
#define WS_HB   768
#define WS_QKV  1536
#define WS_FC   3840
#define WS_Y    6912    // 12 heads * 768
#define WS_T    16128   // 12 (y and T contiguous: zero 9228 floats from WS_Y)

__device__ __forceinline__ void f4add(float4& a, const float4& b) {
  a.x += b.x; a.y += b.y; a.z += b.z; a.w += b.w;
}
__device__ __forceinline__ void f4fma(float4& a, float x, const float4& w) {
  a.x += x * w.x; a.y += x * w.y; a.z += x * w.z; a.w += x * w.w;
}

__device__ __forceinline__ void blockReduce2(float& a, float& b, volatile float* ra, volatile float* rb) {
  int lane = threadIdx.x & 63, wid = threadIdx.x >> 6;
#pragma unroll
  for (int o = 32; o > 0; o >>= 1) { a += __shfl_down(a, o); b += __shfl_down(b, o); }
  if (lane == 0) { ra[wid] = a; rb[wid] = b; }
  __syncthreads();
  if (threadIdx.x == 0) {
    ra[0] = ra[0] + ra[1] + ra[2] + ra[3];
    rb[0] = rb[0] + rb[1] + rb[2] + rb[3];
  }
  __syncthreads();
  a = ra[0]; b = rb[0];
}

__device__ __forceinline__ float gelu(float x) {
  return 0.5f * x * (1.f + tanhf(0.7978845608028654f * (x + 0.044715f * x * x * x)));
}

// blocks 0..8: seed layer-0 qkv bias; blocks 9..11: h(A) = wte[id] + wpe[S]
__global__ void init_kernel(const int* __restrict__ ids, const float* __restrict__ wte,
                            const float* __restrict__ wpe, const float* __restrict__ attn_b,
                            float* __restrict__ wsf) {
  int tid = threadIdx.x, bi = blockIdx.x;
  if (bi < 9) {
    wsf[WS_QKV + bi * 256 + tid] = attn_b[bi * 256 + tid];
  } else {
    int e = (bi - 9) * 256 + tid;
    int id = ids[0];
    wsf[WS_HA + e] = wte[(size_t)id * EMB + e] + wpe[(size_t)S_PAST * EMB + e];
  }
}

// qkv: wqkv[j] += sum_e LN1(h)[e]*attn_w[l][e][j]; 32 rows x 256 cols per block.
// Side duties: by==1 zeros y+T; by==2 seeds wfc with fc bias.
__global__ void ln_gemv4(const float* __restrict__ hvec, const float* __restrict__ g,
                         const float* __restrict__ bb, const float* __restrict__ W,
                         float* __restrict__ out, const float* __restrict__ fc_b,
                         float* __restrict__ wsf, int l) {
  __shared__ float lh[EMB];
  __shared__ float xs[32];
  __shared__ float ra[4], rb[4];
  __shared__ float4 red[4][64];
  int tid = threadIdx.x, lane = tid & 63, wid = tid >> 6;
  int e0 = blockIdx.y * 32;
  float hv0 = hvec[tid], hv1 = hvec[tid + 256], hv2 = hvec[tid + 512];
  int j4 = blockIdx.x * 64 + lane;
  const int N4 = E3 >> 2;
  const float4* p = (const float4*)(W + (size_t)l * EMB * E3) + (size_t)(e0 + wid) * N4 + j4;
  float4 w[8];
#pragma unroll
  for (int i = 0; i < 8; i++) w[i] = p[(size_t)(i * 4) * N4];
  // side duties (tiny, hidden under weight loads)
  if (blockIdx.y == 1) {
    int t0 = blockIdx.x * 256 + tid;
    for (int i = t0; i < 9228; i += 2304) wsf[WS_Y + i] = 0.f;
  } else if (blockIdx.y == 2) {
    int t0 = blockIdx.x * 256 + tid;
    for (int i = t0; i < E4; i += 2304) wsf[WS_FC + i] = fc_b[l * E4 + i];
  }
  float gv = 0.f, bv = 0.f;
  if (tid < 32) { gv = g[l * EMB + e0 + tid]; bv = bb[l * EMB + e0 + tid]; }
  lh[tid] = hv0; lh[tid + 256] = hv1; lh[tid + 512] = hv2;
  float s1 = hv0 + hv1 + hv2;
  float s2 = hv0 * hv0 + hv1 * hv1 + hv2 * hv2;
  blockReduce2(s1, s2, ra, rb);
  float mean = s1 * (1.f / EMB);
  float var = s2 * (1.f / EMB) - mean * mean;
  float rstd = rsqrtf(var + 1e-5f);
  if (tid < 32) xs[tid] = (lh[e0 + tid] - mean) * rstd * gv + bv;
  __syncthreads();
  float4 acc = {0.f, 0.f, 0.f, 0.f};
#pragma unroll
  for (int i = 0; i < 8; i++) f4fma(acc, xs[wid + i * 4], w[i]);
  red[wid][lane] = acc;
  __syncthreads();
  if (wid == 0) {
    float4 a0 = red[0][lane], a1 = red[1][lane], a2 = red[2][lane], a3 = red[3][lane];
    float rx = a0.x + a1.x + a2.x + a3.x;
    float ry = a0.y + a1.y + a2.y + a3.y;
    float rz = a0.z + a1.z + a2.z + a3.z;
    float rw = a0.w + a1.w + a2.w + a3.w;
    float* op = out + (size_t)j4 * 4;
    atomicAdd(op + 0, rx); atomicAdd(op + 1, ry);
    atomicAdd(op + 2, rz); atomicAdd(op + 3, rw);
  }
}

// attention + per-chunk proj partial (M=0 softmax linearity).
// Block (h,c): scores/exp/PV over its 64 keys, KV copy-out, then o_c @ proj_w[h rows]
// accumulated into y[h][768] (16-way fan-in); s_c into T[h].
__global__ __launch_bounds__(256) void attn_kv(
    const float* __restrict__ qkv, const float* __restrict__ pk,
    const float* __restrict__ pv, const float* __restrict__ mask,
    const float* __restrict__ proj_w, float* __restrict__ opk, float* __restrict__ opv,
    float* __restrict__ wsf, int l) {
  // XCD swizzle: g = (bi&7)*24 + (bi>>3) keeps a head's 16 blocks on <=2 XCDs
  int g = (blockIdx.x & 7) * 24 + (blockIdx.x >> 3);
  int h = g >> 4, c = g & 15;
  int tid = threadIdx.x, lane = tid & 63, wid = tid >> 6;
  int sub = tid & 15, grp = tid >> 4;
  __shared__ float4 qs4[16];
  __shared__ float sc[64];
  __shared__ float oc[64];
  __shared__ float4 redo[4][16];
  if (tid < 16) qs4[tid] = ((const float4*)(qkv + h * 64))[tid];
  __syncthreads();
  size_t base = ((size_t)(l * NH + h) * MAXS) * HD;
  const float4* K4 = (const float4*)(pk + base);
  const float4* V4 = (const float4*)(pv + base);
  float4* oK4 = (float4*)(opk + base);
  float4* oV4 = (float4*)(opv + base);
  int t0 = c * 64;
  float4 kreg[4];
#pragma unroll
  for (int i = 0; i < 4; i++) {
    int t = t0 + grp + i * 16;
    kreg[i] = (t == S_PAST) ? ((const float4*)(qkv + EMB + h * 64))[sub] : K4[(size_t)t * 16 + sub];
  }
#pragma unroll
  for (int i = 0; i < 4; i++) {
    int t = t0 + grp + i * 16;
    oK4[(size_t)t * 16 + sub] = kreg[i];
  }
  float4 q4 = qs4[sub];
#pragma unroll
  for (int i = 0; i < 4; i++) {
    int key = grp + i * 16;
    float p = q4.x * kreg[i].x + q4.y * kreg[i].y + q4.z * kreg[i].z + q4.w * kreg[i].w;
    p += __shfl_xor(p, 1); p += __shfl_xor(p, 2);
    p += __shfl_xor(p, 4); p += __shfl_xor(p, 8);
    if (sub == 0) sc[key] = p * 0.125f + (1.f - mask[t0 + key]) * (-1e9f);
  }
  __syncthreads();
  if (wid == 0) {
    float e = expf(sc[lane]);      // M=0: scores bounded ~|2.5|, exp safe
    sc[lane] = e;
    float s = e;
#pragma unroll
    for (int o = 32; o > 0; o >>= 1) s += __shfl_down(s, o);
    if (lane == 0) atomicAdd(wsf + WS_T + h, s);
  }
  __syncthreads();
  float4 vreg[4];
#pragma unroll
  for (int i = 0; i < 4; i++) {
    int t = t0 + grp + i * 16;
    vreg[i] = (t == S_PAST) ? ((const float4*)(qkv + 2 * EMB + h * 64))[sub] : V4[(size_t)t * 16 + sub];
  }
#pragma unroll
  for (int i = 0; i < 4; i++) {
    int t = t0 + grp + i * 16;
    oV4[(size_t)t * 16 + sub] = vreg[i];
  }
  float4 acc = {0.f, 0.f, 0.f, 0.f};
#pragma unroll
  for (int i = 0; i < 4; i++) f4fma(acc, sc[grp + i * 16], vreg[i]);
  acc.x += __shfl_xor(acc.x, 16); acc.y += __shfl_xor(acc.y, 16);
  acc.z += __shfl_xor(acc.z, 16); acc.w += __shfl_xor(acc.w, 16);
  acc.x += __shfl_xor(acc.x, 32); acc.y += __shfl_xor(acc.y, 32);
  acc.z += __shfl_xor(acc.z, 32); acc.w += __shfl_xor(acc.w, 32);
  if (lane < 16) redo[wid][lane] = acc;
  __syncthreads();
  if (tid < 16) {
    float4 a0 = redo[0][tid], a1 = redo[1][tid], a2 = redo[2][tid], a3 = redo[3][tid];
    float4 r;
    r.x = a0.x + a1.x + a2.x + a3.x;
    r.y = a0.y + a1.y + a2.y + a3.y;
    r.z = a0.z + a1.z + a2.z + a3.z;
    r.w = a0.w + a1.w + a2.w + a3.w;
    ((float4*)oc)[tid] = r;
  }
  __syncthreads();
  // per-chunk proj partial: o_c[64] @ proj_w[h*64 .. h*64+64][:] -> y[h][:]
  if (tid < 192) {
    const float4* Wp4 = (const float4*)(proj_w + (size_t)l * EMB * EMB)
                        + (size_t)h * 64 * (EMB >> 2) + tid;
    float4 pa = {0.f, 0.f, 0.f, 0.f};
#pragma unroll
    for (int b = 0; b < 4; b++) {
      float4 w[16];
#pragma unroll
      for (int i = 0; i < 16; i++) w[i] = Wp4[(size_t)(b * 16 + i) * (EMB >> 2)];
#pragma unroll
      for (int i = 0; i < 16; i++) f4fma(pa, oc[b * 16 + i], w[i]);
    }
    float* yp = wsf + WS_Y + h * EMB + tid * 4;
    atomicAdd(yp + 0, pa.x); atomicAdd(yp + 1, pa.y);
    atomicAdd(yp + 2, pa.z); atomicAdd(yp + 3, pa.w);
  }
}

// fc: prologue combines h_new = R + sum_h y_h/T_h + proj_b (block (0,0) writes it to S),
// then LN2 + 32-row x 256-col GEMV into wfc (bias pre-seeded by qkv stage).
__global__ void fc_gemv(const float* __restrict__ R, float* __restrict__ S,
                        const float* __restrict__ proj_b, const float* __restrict__ g2,
                        const float* __restrict__ b2, const float* __restrict__ W,
                        float* __restrict__ wsf, int l) {
  __shared__ float lh[EMB];
  __shared__ float xs[32];
  __shared__ float ra[4], rb[4];
  __shared__ float4 red[4][64];
  int tid = threadIdx.x, lane = tid & 63, wid = tid >> 6;
  int jt = blockIdx.x, et = blockIdx.y, e0 = et * 32;
  // prefetch fc weights (addresses independent of prologue)
  int j4 = jt * 64 + lane;
  const int N4 = E4 >> 2;
  const float4* p = (const float4*)(W + (size_t)l * EMB * E4) + (size_t)(e0 + wid) * N4 + j4;
  float4 w[8];
#pragma unroll
  for (int i = 0; i < 8; i++) w[i] = p[(size_t)(i * 4) * N4];
  // combine proj partials
  float invT[NH];
#pragma unroll
  for (int hh = 0; hh < NH; hh++) invT[hh] = 1.f / wsf[WS_T + hh];
  float hn[3];
#pragma unroll
  for (int k = 0; k < 3; k++) {
    int e = tid + 256 * k;
    float v = R[e] + proj_b[l * EMB + e];
#pragma unroll
    for (int hh = 0; hh < NH; hh++) v += wsf[WS_Y + hh * EMB + e] * invT[hh];
    hn[k] = v;
    lh[e] = v;
  }
  if (jt == 0 && et == 0) {
#pragma unroll
    for (int k = 0; k < 3; k++) S[tid + 256 * k] = hn[k];
  }
  float gv = 0.f, bv = 0.f;
  if (tid < 32) { gv = g2[l * EMB + e0 + tid]; bv = b2[l * EMB + e0 + tid]; }
  float s1 = hn[0] + hn[1] + hn[2];
  float s2 = hn[0] * hn[0] + hn[1] * hn[1] + hn[2] * hn[2];
  blockReduce2(s1, s2, ra, rb);
  float mean = s1 * (1.f / EMB);
  float var = s2 * (1.f / EMB) - mean * mean;
  float rstd = rsqrtf(var + 1e-5f);
  if (tid < 32) xs[tid] = (lh[e0 + tid] - mean) * rstd * gv + bv;
  __syncthreads();
  float4 acc = {0.f, 0.f, 0.f, 0.f};
#pragma unroll
  for (int i = 0; i < 8; i++) f4fma(acc, xs[wid + i * 4], w[i]);
  red[wid][lane] = acc;
  __syncthreads();
  if (wid == 0) {
    float4 a0 = red[0][lane], a1 = red[1][lane], a2 = red[2][lane], a3 = red[3][lane];
    float rx = a0.x + a1.x + a2.x + a3.x;
    float ry = a0.y + a1.y + a2.y + a3.y;
    float rz = a0.z + a1.z + a2.z + a3.z;
    float rw = a0.w + a1.w + a2.w + a3.w;
    float* op = wsf + WS_FC + (size_t)j4 * 4;
    atomicAdd(op + 0, rx); atomicAdd(op + 1, ry);
    atomicAdd(op + 2, rz); atomicAdd(op + 3, rw);
  }
}

// mlp: S[j] += sum_e gelu(wfc[e]) * mlp_w[l][e][j]; 64 rows x 256 cols; seeds next qkv
__global__ void mlp_gemv4(const float* __restrict__ fcv, const float* __restrict__ W,
                          const float* __restrict__ bias, const float* __restrict__ attn_b,
                          float* __restrict__ hout, float* __restrict__ qkv, int l) {
  __shared__ float xs[64];
  __shared__ float4 red[4][64];
  int tid = threadIdx.x, lane = tid & 63, wid = tid >> 6;
  int e0 = blockIdx.y * 64;
  int j4 = blockIdx.x * 64 + lane;
  const int N4 = EMB >> 2;
  const float4* p = (const float4*)(W + (size_t)l * E4 * EMB) + (size_t)(e0 + wid) * N4 + j4;
  float4 w[16];
#pragma unroll
  for (int i = 0; i < 16; i++) w[i] = p[(size_t)(i * 4) * N4];
  if (tid < 64) xs[tid] = gelu(fcv[e0 + tid]);
  int bid = blockIdx.y * 3 + blockIdx.x;
  if (l + 1 < NL && bid < 9) qkv[bid * 256 + tid] = attn_b[(l + 1) * E3 + bid * 256 + tid];
  __syncthreads();
  float4 acc = {0.f, 0.f, 0.f, 0.f};
#pragma unroll
  for (int i = 0; i < 16; i++) f4fma(acc, xs[wid + i * 4], w[i]);
  red[wid][lane] = acc;
  __syncthreads();
  if (wid == 0) {
    float4 a0 = red[0][lane], a1 = red[1][lane], a2 = red[2][lane], a3 = red[3][lane];
    float rx = a0.x + a1.x + a2.x + a3.x;
    float ry = a0.y + a1.y + a2.y + a3.y;
    float rz = a0.z + a1.z + a2.z + a3.z;
    float rw = a0.w + a1.w + a2.w + a3.w;
    if (blockIdx.y == 0) {
      const float* bp = bias + l * EMB + j4 * 4;
      rx += bp[0]; ry += bp[1]; rz += bp[2]; rw += bp[3];
    }
    float* op = hout + (size_t)j4 * 4;
    atomicAdd(op + 0, rx); atomicAdd(op + 1, ry);
    atomicAdd(op + 2, rz); atomicAdd(op + 3, rw);
  }
}

// final LN fused into logits
__global__ void logits_lnf(const float* __restrict__ hvec, const float* __restrict__ g,
                           const float* __restrict__ b, const float* __restrict__ wte,
                           float* __restrict__ out) {
  __shared__ __align__(16) float4 xs4[192];
  __shared__ float ra[4], rb[4];
  int tid = threadIdx.x, lane = tid & 63, wid = tid >> 6;
  float hv0 = hvec[tid], hv1 = hvec[tid + 256], hv2 = hvec[tid + 512];
  int v = blockIdx.x * 4 + wid;
  float4 a0 = {0,0,0,0}, a1 = {0,0,0,0}, a2 = {0,0,0,0};
  if (v < NV) {
    const float4* row = (const float4*)(wte + (size_t)v * EMB);
    a0 = row[lane]; a1 = row[lane + 64]; a2 = row[lane + 128];
  }
  float s1 = hv0 + hv1 + hv2;
  float s2 = hv0 * hv0 + hv1 * hv1 + hv2 * hv2;
  blockReduce2(s1, s2, ra, rb);
  float mean = s1 * (1.f / EMB);
  float var = s2 * (1.f / EMB) - mean * mean;
  float rstd = rsqrtf(var + 1e-5f);
  ((float*)xs4)[tid]       = (hv0 - mean) * rstd * g[tid]       + b[tid];
  ((float*)xs4)[tid + 256] = (hv1 - mean) * rstd * g[tid + 256] + b[tid + 256];
  ((float*)xs4)[tid + 512] = (hv2 - mean) * rstd * g[tid + 512] + b[tid + 512];
  __syncthreads();
  if (v >= NV) return;
  float4 x0 = xs4[lane], x1 = xs4[lane + 64], x2 = xs4[lane + 128];
  float acc = a0.x * x0.x + a0.y * x0.y + a0.z * x0.z + a0.w * x0.w
            + a1.x * x1.x + a1.y * x1.y + a1.z * x1.z + a1.w * x1.w
            + a2.x * x2.x + a2.y * x2.y + a2.z * x2.z + a2.w * x2.w;
#pragma unroll
  for (int o = 32; o > 0; o >>= 1) acc += __shfl_down(acc, o);
  if (lane == 0) out[v] = acc;
}

extern "C" void kernel_launch(void* const* d_in, const int* in_sizes, int n_in,
                              void* d_out, int out_size, void* d_ws, size_t ws_size,
                              hipStream_t stream) {
  const int* input_ids = (const int*)d_in[0];
  const float* past_key = (const float*)d_in[1];
  const float* past_value = (const float*)d_in[2];
  const float* mask = (const float*)d_in[4];
  const float* wte = (const float*)d_in[5];
  const float* wpe = (const float*)d_in[6];
  const float* ln1_g = (const float*)d_in[7];
  const float* ln1_b = (const float*)d_in[8];
  const float* attn_w = (const float*)d_in[9];
  const float* attn_b = (const float*)d_in[10];
  const float* proj_w = (const float*)d_in[11];
  const float* proj_b = (const float*)d_in[12];
  const float* ln2_g = (const float*)d_in[13];
  const float* ln2_b = (const float*)d_in[14];
  const float* fc_w = (const float*)d_in[15];
  const float* fc_b = (const float*)d_in[16];
  const float* mlp_w = (const float*)d_in[17];
  const float* mlp_b = (const float*)d_in[18];
  const float* lnf_g = (const float*)d_in[19];
  const float* lnf_b = (const float*)d_in[20];

  float* out = (float*)d_out;
  float* out_logits = out;
  float* out_pk = out + NV;
  float* out_pv = out_pk + (size_t)NL * NH * MAXS * HD;

  float* wsf = (float*)d_ws;
  float* wqkv = wsf + WS_QKV;
  float* wfc = wsf + WS_FC;

  init_kernel<<<12, 256, 0, stream>>>(input_ids, wte, wpe, attn_b, wsf);

  for (int l = 0; l < NL; l++) {
    float* R = wsf + ((l & 1) ? WS_HB : WS_HA);
    float* S = wsf + ((l & 1) ? WS_HA : WS_HB);
    ln_gemv4<<<dim3(9, 24), 256, 0, stream>>>(R, ln1_g, ln1_b, attn_w, wqkv, fc_b, wsf, l);
    attn_kv<<<192, 256, 0, stream>>>(wqkv, past_key, past_value, mask, proj_w,
                                     out_pk, out_pv, wsf, l);
    fc_gemv<<<dim3(12, 24), 256, 0, stream>>>(R, S, proj_b, ln2_g, ln2_b, fc_w, wsf, l);
    mlp_gemv4<<<dim3(3, 48), 256, 0, stream>>>(wfc, mlp_w, mlp_b, attn_b, S, wqkv, l);
  }
  logits_lnf<<<12565, 256, 0, stream>>>(wsf + WS_HA, lnf_g, lnf_b, wte, out_logits);
}